// Round 1
// baseline (1207.523 us; speedup 1.0000x reference)
//
#include <hip/hip_runtime.h>

#define N_NODES 50000
#define N_EDGES 640000
#define D 128               // D_IN == D_OUT == 128
#define ROWS_PER_BLOCK 64

// ---------------------------------------------------------------------------
// Kernel 1: zero the aggregation buffer (workspace)
// ---------------------------------------------------------------------------
__global__ __launch_bounds__(256) void zero_kernel(float4* __restrict__ p, int n4) {
    int i = blockIdx.x * 256 + threadIdx.x;
    if (i < n4) p[i] = make_float4(0.f, 0.f, 0.f, 0.f);
}

// ---------------------------------------------------------------------------
// Kernel 2: edge scatter  agg[dst[e]] += features[src[e]]
// One thread per (edge, float4-chunk): 32 threads cover one edge's 128 floats.
// Consecutive 32-thread groups share src/dst loads (cache broadcast) and issue
// coalesced 128B float4 gathers. HW f32 atomics via unsafeAtomicAdd
// (global_atomic_add_f32, not a CAS loop).
// ---------------------------------------------------------------------------
__global__ __launch_bounds__(256) void scatter_kernel(
        const float4* __restrict__ feat4,
        const int* __restrict__ src,
        const int* __restrict__ dst,
        float* __restrict__ agg) {
    int idx = blockIdx.x * 256 + threadIdx.x;      // E * 32 tasks
    int e = idx >> 5;
    int c = idx & 31;
    if (e >= N_EDGES) return;
    int s = src[e];
    int d = dst[e];
    float4 v = feat4[s * (D / 4) + c];
    float* o = agg + d * D + c * 4;
    unsafeAtomicAdd(o + 0, v.x);
    unsafeAtomicAdd(o + 1, v.y);
    unsafeAtomicAdd(o + 2, v.z);
    unsafeAtomicAdd(o + 3, v.w);
}

// ---------------------------------------------------------------------------
// Kernel 3: out = agg @ W + b     (fp32, vector ALU — no fp32 MFMA on CDNA4)
// W (128x128, 64KB) staged in LDS once per block. Block = 256 threads:
// 32 col-quads x 8 rows; each thread computes a float4 of one output row.
// ---------------------------------------------------------------------------
__global__ __launch_bounds__(256) void gemm_kernel(
        const float* __restrict__ agg,
        const float* __restrict__ W,
        const float* __restrict__ b,
        float* __restrict__ out) {
    __shared__ float4 Wl[D * D / 4];               // 64 KB: Wl[k*32 + col4] = W[k][4c..4c+3]
    const float4* W4 = (const float4*)W;
    for (int i = threadIdx.x; i < D * D / 4; i += 256) Wl[i] = W4[i];
    __syncthreads();

    int col4 = threadIdx.x & 31;                   // which 4-col group
    int rrow = threadIdx.x >> 5;                   // 0..7
    int base = blockIdx.x * ROWS_PER_BLOCK;
    float4 bb = ((const float4*)b)[col4];

    for (int it = 0; it < ROWS_PER_BLOCK / 8; ++it) {
        int row = base + it * 8 + rrow;
        if (row >= N_NODES) return;                // no syncs after this point
        const float4* arow = (const float4*)(agg + (size_t)row * D);
        float4 acc = bb;
        #pragma unroll
        for (int k4 = 0; k4 < D / 4; ++k4) {
            float4 a  = arow[k4];                  // broadcast across the row's lanes
            float4 w0 = Wl[(k4 * 4 + 0) * 32 + col4];
            float4 w1 = Wl[(k4 * 4 + 1) * 32 + col4];
            float4 w2 = Wl[(k4 * 4 + 2) * 32 + col4];
            float4 w3 = Wl[(k4 * 4 + 3) * 32 + col4];
            acc.x += a.x * w0.x + a.y * w1.x + a.z * w2.x + a.w * w3.x;
            acc.y += a.x * w0.y + a.y * w1.y + a.z * w2.y + a.w * w3.y;
            acc.z += a.x * w0.z + a.y * w1.z + a.z * w2.z + a.w * w3.z;
            acc.w += a.x * w0.w + a.y * w1.w + a.z * w2.w + a.w * w3.w;
        }
        ((float4*)(out + (size_t)row * D))[col4] = acc;
    }
}

// ---------------------------------------------------------------------------
extern "C" void kernel_launch(void* const* d_in, const int* in_sizes, int n_in,
                              void* d_out, int out_size, void* d_ws, size_t ws_size,
                              hipStream_t stream) {
    const float* feat = (const float*)d_in[0];   // [50000,128] f32
    const int*   src  = (const int*)d_in[1];     // [640000] (int32 on device)
    const int*   dst  = (const int*)d_in[2];     // [640000]
    const float* W    = (const float*)d_in[3];   // [128,128] f32
    const float* b    = (const float*)d_in[4];   // [1,128] f32
    float* out = (float*)d_out;                  // [50000,128] f32
    float* agg = (float*)d_ws;                   // 25.6 MB scratch

    const int n4 = N_NODES * D / 4;
    zero_kernel<<<(n4 + 255) / 256, 256, 0, stream>>>((float4*)agg, n4);

    const long long tasks = (long long)N_EDGES * 32;
    scatter_kernel<<<(int)((tasks + 255) / 256), 256, 0, stream>>>(
        (const float4*)feat, src, dst, agg);

    gemm_kernel<<<(N_NODES + ROWS_PER_BLOCK - 1) / ROWS_PER_BLOCK, 256, 0, stream>>>(
        agg, W, b, out);
}

// Round 2
// 292.434 us; speedup vs baseline: 4.1292x; 4.1292x over previous
//
#include <hip/hip_runtime.h>

#define N_NODES 50000
#define N_EDGES 640000
#define D 128               // D_IN == D_OUT == 128

// ---------------------------------------------------------------------------
// Workspace layout (ints):
//   deg    [50176]   per-node in-degree (padded to 1024*49)
//   off    [50048]   CSR row offsets (needs 50001)
//   cursor [50048]   fill cursors
//   esrc   [640000]  src node id per edge, grouped by dst
// Total ~3.16 MB. d_out doubles as the 25.6 MB aggregation buffer.
// ---------------------------------------------------------------------------
#define DEG_PAD 50176       // 1024 * 49
#define OFF_PAD 50048

// K1: zero the degree array (ws is poisoned 0xAA every call)
__global__ __launch_bounds__(256) void zero_deg_kernel(int4* __restrict__ p) {
    int i = blockIdx.x * 256 + threadIdx.x;
    if (i < DEG_PAD / 4) p[i] = make_int4(0, 0, 0, 0);
}

// K2: histogram of dst -> deg  (int atomics only)
__global__ __launch_bounds__(256) void hist_kernel(const int* __restrict__ dst,
                                                   int* __restrict__ deg) {
    int e = blockIdx.x * 256 + threadIdx.x;
    if (e < N_EDGES) atomicAdd(&deg[dst[e]], 1);
}

// K3: single-block exclusive scan of deg -> off (+ cursor init).
// 1024 threads x 49 elements each; Hillis-Steele block scan of partials.
__global__ __launch_bounds__(1024) void scan_kernel(const int* __restrict__ deg,
                                                    int* __restrict__ off,
                                                    int* __restrict__ cursor) {
    __shared__ int part[1024];
    const int t = threadIdx.x;
    const int base = t * 49;
    int local[49];
    int sum = 0;
    #pragma unroll
    for (int j = 0; j < 49; ++j) {
        local[j] = sum;                       // exclusive prefix within thread
        sum += deg[base + j];                 // deg padded region is zeroed
    }
    part[t] = sum;
    __syncthreads();
    for (int s = 1; s < 1024; s <<= 1) {
        int v = (t >= s) ? part[t - s] : 0;
        __syncthreads();
        part[t] += v;
        __syncthreads();
    }
    const int excl = (t == 0) ? 0 : part[t - 1];
    #pragma unroll
    for (int j = 0; j < 49; ++j) {
        int i = base + j;
        if (i < N_NODES) {
            int o = excl + local[j];
            off[i] = o;
            cursor[i] = o;
        }
    }
    if (t == 1023) off[N_NODES] = part[1023]; // == N_EDGES
}

// K4: fill CSR edge list (src ids grouped by dst)
__global__ __launch_bounds__(256) void fill_kernel(const int* __restrict__ src,
                                                   const int* __restrict__ dst,
                                                   int* __restrict__ cursor,
                                                   int* __restrict__ esrc) {
    int e = blockIdx.x * 256 + threadIdx.x;
    if (e < N_EDGES) {
        int p = atomicAdd(&cursor[dst[e]], 1);
        esrc[p] = src[e];
    }
}

// K5: per-node gather-sum. One 64-lane wave per node; lane owns a float2
// column slice (coalesced 512B row loads, L2/L3-served). No atomics.
// Writes agg into d_out.
__global__ __launch_bounds__(256) void gather_kernel(const float2* __restrict__ feat2,
                                                     const int* __restrict__ off,
                                                     const int* __restrict__ esrc,
                                                     float2* __restrict__ agg2) {
    int node = (blockIdx.x * 256 + threadIdx.x) >> 6;
    int lane = threadIdx.x & 63;
    if (node >= N_NODES) return;
    int beg = off[node], end = off[node + 1];
    float2 acc = make_float2(0.f, 0.f);
    int p = beg;
    for (; p + 2 <= end; p += 2) {          // 2x unroll for load ILP
        int s0 = esrc[p];
        int s1 = esrc[p + 1];
        float2 v0 = feat2[(size_t)s0 * 64 + lane];
        float2 v1 = feat2[(size_t)s1 * 64 + lane];
        acc.x += v0.x + v1.x;
        acc.y += v0.y + v1.y;
    }
    if (p < end) {
        int s = esrc[p];
        float2 v = feat2[(size_t)s * 64 + lane];
        acc.x += v.x;
        acc.y += v.y;
    }
    agg2[(size_t)node * 64 + lane] = acc;
}

// K6: out = out @ W + b, IN PLACE. Register-tiled: each thread computes
// 4 rows x 1 float4 col-group (reuses each LDS W read 4x). Safe in place:
// each row is read and written by the same lockstep 32-lane half-wave,
// and the stores depend on all loads.
__global__ __launch_bounds__(256) void gemm_kernel(const float* __restrict__ W,
                                                   const float* __restrict__ b,
                                                   float* out) {
    __shared__ float4 Wl[D * 32];             // 64 KB: Wl[k*32 + c4] = W[k][4c..]
    const float4* W4 = (const float4*)W;
    for (int i = threadIdx.x; i < D * 32; i += 256) Wl[i] = W4[i];
    __syncthreads();

    const int c4 = threadIdx.x & 31;
    const int rg = threadIdx.x >> 5;          // 0..7
    const int row0 = blockIdx.x * 32 + rg * 4;
    if (row0 >= N_NODES) return;              // N_NODES % 4 == 0 -> all-or-none

    const float4 bb = ((const float4*)b)[c4];
    float4 acc0 = bb, acc1 = bb, acc2 = bb, acc3 = bb;
    const float4* a0 = (const float4*)(out + (size_t)(row0 + 0) * D);
    const float4* a1 = (const float4*)(out + (size_t)(row0 + 1) * D);
    const float4* a2 = (const float4*)(out + (size_t)(row0 + 2) * D);
    const float4* a3 = (const float4*)(out + (size_t)(row0 + 3) * D);

    #pragma unroll 8
    for (int k4 = 0; k4 < 32; ++k4) {
        float4 A0 = a0[k4], A1 = a1[k4], A2 = a2[k4], A3 = a3[k4];
        float4 w0 = Wl[(k4 * 4 + 0) * 32 + c4];
        float4 w1 = Wl[(k4 * 4 + 1) * 32 + c4];
        float4 w2 = Wl[(k4 * 4 + 2) * 32 + c4];
        float4 w3 = Wl[(k4 * 4 + 3) * 32 + c4];
        acc0.x += A0.x*w0.x + A0.y*w1.x + A0.z*w2.x + A0.w*w3.x;
        acc0.y += A0.x*w0.y + A0.y*w1.y + A0.z*w2.y + A0.w*w3.y;
        acc0.z += A0.x*w0.z + A0.y*w1.z + A0.z*w2.z + A0.w*w3.z;
        acc0.w += A0.x*w0.w + A0.y*w1.w + A0.z*w2.w + A0.w*w3.w;
        acc1.x += A1.x*w0.x + A1.y*w1.x + A1.z*w2.x + A1.w*w3.x;
        acc1.y += A1.x*w0.y + A1.y*w1.y + A1.z*w2.y + A1.w*w3.y;
        acc1.z += A1.x*w0.z + A1.y*w1.z + A1.z*w2.z + A1.w*w3.z;
        acc1.w += A1.x*w0.w + A1.y*w1.w + A1.z*w2.w + A1.w*w3.w;
        acc2.x += A2.x*w0.x + A2.y*w1.x + A2.z*w2.x + A2.w*w3.x;
        acc2.y += A2.x*w0.y + A2.y*w1.y + A2.z*w2.y + A2.w*w3.y;
        acc2.z += A2.x*w0.z + A2.y*w1.z + A2.z*w2.z + A2.w*w3.z;
        acc2.w += A2.x*w0.w + A2.y*w1.w + A2.z*w2.w + A2.w*w3.w;
        acc3.x += A3.x*w0.x + A3.y*w1.x + A3.z*w2.x + A3.w*w3.x;
        acc3.y += A3.x*w0.y + A3.y*w1.y + A3.z*w2.y + A3.w*w3.y;
        acc3.z += A3.x*w0.z + A3.y*w1.z + A3.z*w2.z + A3.w*w3.z;
        acc3.w += A3.x*w0.w + A3.y*w1.w + A3.z*w2.w + A3.w*w3.w;
    }
    ((float4*)(out + (size_t)(row0 + 0) * D))[c4] = acc0;
    ((float4*)(out + (size_t)(row0 + 1) * D))[c4] = acc1;
    ((float4*)(out + (size_t)(row0 + 2) * D))[c4] = acc2;
    ((float4*)(out + (size_t)(row0 + 3) * D))[c4] = acc3;
}

// ---------------------------------------------------------------------------
extern "C" void kernel_launch(void* const* d_in, const int* in_sizes, int n_in,
                              void* d_out, int out_size, void* d_ws, size_t ws_size,
                              hipStream_t stream) {
    const float* feat = (const float*)d_in[0];   // [50000,128] f32
    const int*   src  = (const int*)d_in[1];     // [640000] int32
    const int*   dst  = (const int*)d_in[2];     // [640000] int32
    const float* W    = (const float*)d_in[3];   // [128,128] f32
    const float* b    = (const float*)d_in[4];   // [1,128]   f32
    float* out = (float*)d_out;                  // [50000,128] f32 (also agg buffer)

    int* deg    = (int*)d_ws;
    int* off    = deg + DEG_PAD;
    int* cursor = off + OFF_PAD;
    int* esrc   = cursor + OFF_PAD;

    zero_deg_kernel<<<(DEG_PAD / 4 + 255) / 256, 256, 0, stream>>>((int4*)deg);
    hist_kernel<<<(N_EDGES + 255) / 256, 256, 0, stream>>>(dst, deg);
    scan_kernel<<<1, 1024, 0, stream>>>(deg, off, cursor);
    fill_kernel<<<(N_EDGES + 255) / 256, 256, 0, stream>>>(src, dst, cursor, esrc);
    gather_kernel<<<(N_NODES * 64 + 255) / 256, 256, 0, stream>>>(
        (const float2*)feat, off, esrc, (float2*)out);
    gemm_kernel<<<(N_NODES + 31) / 32, 256, 0, stream>>>(W, b, out);
}

// Round 3
// 244.201 us; speedup vs baseline: 4.9448x; 1.1975x over previous
//
#include <hip/hip_runtime.h>

#define N_NODES 50000
#define N_EDGES 640000
#define D 128               // D_IN == D_OUT == 128

// ---------------------------------------------------------------------------
// Workspace layout (ints):
//   deg     [50176]   per-node in-degree (padded: 196 blocks * 256)
//   off     [50048]   CSR row offsets (needs 50001)
//   cursor  [50048]   fill cursors
//   partial [256]     per-block sums for the scan
//   esrc    [640000]  src node id per edge, grouped by dst
// Total ~3.16 MB. d_out doubles as the 25.6 MB aggregation buffer.
// ---------------------------------------------------------------------------
#define DEG_PAD 50176       // 196 * 256
#define OFF_PAD 50048
#define SCAN_BLOCKS 196

// K1: zero the degree array (ws is poisoned 0xAA every call)
__global__ __launch_bounds__(256) void zero_deg_kernel(int4* __restrict__ p) {
    int i = blockIdx.x * 256 + threadIdx.x;
    if (i < DEG_PAD / 4) p[i] = make_int4(0, 0, 0, 0);
}

// K2: histogram of dst -> deg  (int atomics only)
__global__ __launch_bounds__(256) void hist_kernel(const int* __restrict__ dst,
                                                   int* __restrict__ deg) {
    int e = blockIdx.x * 256 + threadIdx.x;
    if (e < N_EDGES) atomicAdd(&deg[dst[e]], 1);
}

// K3a: per-block reduce of deg -> partial[SCAN_BLOCKS]
__global__ __launch_bounds__(256) void scan_reduce_kernel(const int* __restrict__ deg,
                                                          int* __restrict__ partial) {
    __shared__ int sm[256];
    int t = threadIdx.x;
    sm[t] = deg[blockIdx.x * 256 + t];
    __syncthreads();
    for (int s = 128; s > 0; s >>= 1) {
        if (t < s) sm[t] += sm[t + s];
        __syncthreads();
    }
    if (t == 0) partial[blockIdx.x] = sm[0];
}

// K3b: exclusive scan of partial[SCAN_BLOCKS] (single tiny block)
__global__ __launch_bounds__(256) void scan_partials_kernel(int* __restrict__ partial) {
    __shared__ int sm[256];
    int t = threadIdx.x;
    int v = (t < SCAN_BLOCKS) ? partial[t] : 0;
    sm[t] = v;
    __syncthreads();
    for (int s = 1; s < 256; s <<= 1) {
        int x = (t >= s) ? sm[t - s] : 0;
        __syncthreads();
        sm[t] += x;
        __syncthreads();
    }
    if (t < SCAN_BLOCKS) partial[t] = sm[t] - v;   // exclusive
}

// K3c: downsweep — block-local exclusive scan + partial prefix -> off, cursor
__global__ __launch_bounds__(256) void scan_down_kernel(const int* __restrict__ deg,
                                                        const int* __restrict__ partial,
                                                        int* __restrict__ off,
                                                        int* __restrict__ cursor) {
    __shared__ int sm[256];
    int t = threadIdx.x;
    int i = blockIdx.x * 256 + t;
    int v = deg[i];
    sm[t] = v;
    __syncthreads();
    for (int s = 1; s < 256; s <<= 1) {
        int x = (t >= s) ? sm[t - s] : 0;
        __syncthreads();
        sm[t] += x;
        __syncthreads();
    }
    if (i < N_NODES) {
        int o = partial[blockIdx.x] + sm[t] - v;   // global exclusive prefix
        off[i] = o;
        cursor[i] = o;
    }
    if (i == 0) off[N_NODES] = N_EDGES;            // total is a compile-time constant
}

// K4: fill CSR edge list (src ids grouped by dst)
__global__ __launch_bounds__(256) void fill_kernel(const int* __restrict__ src,
                                                   const int* __restrict__ dst,
                                                   int* __restrict__ cursor,
                                                   int* __restrict__ esrc) {
    int e = blockIdx.x * 256 + threadIdx.x;
    if (e < N_EDGES) {
        int p = atomicAdd(&cursor[dst[e]], 1);
        esrc[p] = src[e];
    }
}

// K5: per-node gather-sum. One 64-lane wave per node; lane owns a float2
// column slice (coalesced 512B row loads, L2/L3-served). No atomics.
// Writes agg into d_out.
__global__ __launch_bounds__(256) void gather_kernel(const float2* __restrict__ feat2,
                                                     const int* __restrict__ off,
                                                     const int* __restrict__ esrc,
                                                     float2* __restrict__ agg2) {
    int node = (blockIdx.x * 256 + threadIdx.x) >> 6;
    int lane = threadIdx.x & 63;
    if (node >= N_NODES) return;
    int beg = off[node], end = off[node + 1];
    float2 acc = make_float2(0.f, 0.f);
    int p = beg;
    for (; p + 2 <= end; p += 2) {          // 2x unroll for load ILP
        int s0 = esrc[p];
        int s1 = esrc[p + 1];
        float2 v0 = feat2[(size_t)s0 * 64 + lane];
        float2 v1 = feat2[(size_t)s1 * 64 + lane];
        acc.x += v0.x + v1.x;
        acc.y += v0.y + v1.y;
    }
    if (p < end) {
        int s = esrc[p];
        float2 v = feat2[(size_t)s * 64 + lane];
        acc.x += v.x;
        acc.y += v.y;
    }
    agg2[(size_t)node * 64 + lane] = acc;
}

// K6: out = out @ W + b, IN PLACE. Register-tiled: each thread computes
// 4 rows x 1 float4 col-group (reuses each LDS W read 4x). Safe in place:
// each row is read and written by the same lockstep 32-lane half-wave,
// and the stores depend on all loads.
__global__ __launch_bounds__(256) void gemm_kernel(const float* __restrict__ W,
                                                   const float* __restrict__ b,
                                                   float* out) {
    __shared__ float4 Wl[D * 32];             // 64 KB: Wl[k*32 + c4] = W[k][4c..]
    const float4* W4 = (const float4*)W;
    for (int i = threadIdx.x; i < D * 32; i += 256) Wl[i] = W4[i];
    __syncthreads();

    const int c4 = threadIdx.x & 31;
    const int rg = threadIdx.x >> 5;          // 0..7
    const int row0 = blockIdx.x * 32 + rg * 4;
    if (row0 >= N_NODES) return;              // N_NODES % 4 == 0 -> all-or-none

    const float4 bb = ((const float4*)b)[c4];
    float4 acc0 = bb, acc1 = bb, acc2 = bb, acc3 = bb;
    const float4* a0 = (const float4*)(out + (size_t)(row0 + 0) * D);
    const float4* a1 = (const float4*)(out + (size_t)(row0 + 1) * D);
    const float4* a2 = (const float4*)(out + (size_t)(row0 + 2) * D);
    const float4* a3 = (const float4*)(out + (size_t)(row0 + 3) * D);

    #pragma unroll 8
    for (int k4 = 0; k4 < 32; ++k4) {
        float4 A0 = a0[k4], A1 = a1[k4], A2 = a2[k4], A3 = a3[k4];
        float4 w0 = Wl[(k4 * 4 + 0) * 32 + c4];
        float4 w1 = Wl[(k4 * 4 + 1) * 32 + c4];
        float4 w2 = Wl[(k4 * 4 + 2) * 32 + c4];
        float4 w3 = Wl[(k4 * 4 + 3) * 32 + c4];
        acc0.x += A0.x*w0.x + A0.y*w1.x + A0.z*w2.x + A0.w*w3.x;
        acc0.y += A0.x*w0.y + A0.y*w1.y + A0.z*w2.y + A0.w*w3.y;
        acc0.z += A0.x*w0.z + A0.y*w1.z + A0.z*w2.z + A0.w*w3.z;
        acc0.w += A0.x*w0.w + A0.y*w1.w + A0.z*w2.w + A0.w*w3.w;
        acc1.x += A1.x*w0.x + A1.y*w1.x + A1.z*w2.x + A1.w*w3.x;
        acc1.y += A1.x*w0.y + A1.y*w1.y + A1.z*w2.y + A1.w*w3.y;
        acc1.z += A1.x*w0.z + A1.y*w1.z + A1.z*w2.z + A1.w*w3.z;
        acc1.w += A1.x*w0.w + A1.y*w1.w + A1.z*w2.w + A1.w*w3.w;
        acc2.x += A2.x*w0.x + A2.y*w1.x + A2.z*w2.x + A2.w*w3.x;
        acc2.y += A2.x*w0.y + A2.y*w1.y + A2.z*w2.y + A2.w*w3.y;
        acc2.z += A2.x*w0.z + A2.y*w1.z + A2.z*w2.z + A2.w*w3.z;
        acc2.w += A2.x*w0.w + A2.y*w1.w + A2.z*w2.w + A2.w*w3.w;
        acc3.x += A3.x*w0.x + A3.y*w1.x + A3.z*w2.x + A3.w*w3.x;
        acc3.y += A3.x*w0.y + A3.y*w1.y + A3.z*w2.y + A3.w*w3.y;
        acc3.z += A3.x*w0.z + A3.y*w1.z + A3.z*w2.z + A3.w*w3.z;
        acc3.w += A3.x*w0.w + A3.y*w1.w + A3.z*w2.w + A3.w*w3.w;
    }
    ((float4*)(out + (size_t)(row0 + 0) * D))[c4] = acc0;
    ((float4*)(out + (size_t)(row0 + 1) * D))[c4] = acc1;
    ((float4*)(out + (size_t)(row0 + 2) * D))[c4] = acc2;
    ((float4*)(out + (size_t)(row0 + 3) * D))[c4] = acc3;
}

// ---------------------------------------------------------------------------
extern "C" void kernel_launch(void* const* d_in, const int* in_sizes, int n_in,
                              void* d_out, int out_size, void* d_ws, size_t ws_size,
                              hipStream_t stream) {
    const float* feat = (const float*)d_in[0];   // [50000,128] f32
    const int*   src  = (const int*)d_in[1];     // [640000] int32
    const int*   dst  = (const int*)d_in[2];     // [640000] int32
    const float* W    = (const float*)d_in[3];   // [128,128] f32
    const float* b    = (const float*)d_in[4];   // [1,128]   f32
    float* out = (float*)d_out;                  // [50000,128] f32 (also agg buffer)

    int* deg     = (int*)d_ws;
    int* off     = deg + DEG_PAD;
    int* cursor  = off + OFF_PAD;
    int* partial = cursor + OFF_PAD;
    int* esrc    = partial + 256;

    zero_deg_kernel<<<(DEG_PAD / 4 + 255) / 256, 256, 0, stream>>>((int4*)deg);
    hist_kernel<<<(N_EDGES + 255) / 256, 256, 0, stream>>>(dst, deg);
    scan_reduce_kernel<<<SCAN_BLOCKS, 256, 0, stream>>>(deg, partial);
    scan_partials_kernel<<<1, 256, 0, stream>>>(partial);
    scan_down_kernel<<<SCAN_BLOCKS, 256, 0, stream>>>(deg, partial, off, cursor);
    fill_kernel<<<(N_EDGES + 255) / 256, 256, 0, stream>>>(src, dst, cursor, esrc);
    gather_kernel<<<(N_NODES * 64 + 255) / 256, 256, 0, stream>>>(
        (const float2*)feat, off, esrc, (float2*)out);
    gemm_kernel<<<(N_NODES + 31) / 32, 256, 0, stream>>>(W, b, out);
}

// Round 4
// 221.146 us; speedup vs baseline: 5.4603x; 1.1043x over previous
//
#include <hip/hip_runtime.h>

#define N_NODES 50000
#define N_EDGES 640000
#define D 128               // D_IN == D_OUT == 128

// ---------------------------------------------------------------------------
// Restructured (transform-first): out = segment_sum((feat @ W)[src]) + b
//   K6  gemm_feat: Y = feat @ W   (f32 math, Y stored bf16 — 12.8 MB)
//   K5  gather:    out[d] = sum_{e:dst=d} Y[src[e]] + b   (f32 accum)
// Workspace: Y bf16 [50000*128] then ints:
//   deg[50176] off[50048] cursor[50048] partial[256] esrc[640000]
// Total ~16.0 MB (ws >= 25.6 MB proven in R1).
// ---------------------------------------------------------------------------
#define DEG_PAD 50176       // 196 * 256
#define OFF_PAD 50048
#define SCAN_BLOCKS 196
#define ROWS_PB 128         // gemm rows per block (16 slots x 8 rows)

static __device__ inline unsigned short f2bf(float f) {   // RNE f32 -> bf16
    unsigned u = __float_as_uint(f);
    u += 0x7FFFu + ((u >> 16) & 1u);
    return (unsigned short)(u >> 16);
}

// K1: zero the degree array (ws is poisoned 0xAA every call)
__global__ __launch_bounds__(256) void zero_deg_kernel(int4* __restrict__ p) {
    int i = blockIdx.x * 256 + threadIdx.x;
    if (i < DEG_PAD / 4) p[i] = make_int4(0, 0, 0, 0);
}

// K2: histogram of dst -> deg  (int atomics only)
__global__ __launch_bounds__(256) void hist_kernel(const int* __restrict__ dst,
                                                   int* __restrict__ deg) {
    int e = blockIdx.x * 256 + threadIdx.x;
    if (e < N_EDGES) atomicAdd(&deg[dst[e]], 1);
}

// K3a: per-block reduce of deg -> partial[SCAN_BLOCKS]
__global__ __launch_bounds__(256) void scan_reduce_kernel(const int* __restrict__ deg,
                                                          int* __restrict__ partial) {
    __shared__ int sm[256];
    int t = threadIdx.x;
    sm[t] = deg[blockIdx.x * 256 + t];
    __syncthreads();
    for (int s = 128; s > 0; s >>= 1) {
        if (t < s) sm[t] += sm[t + s];
        __syncthreads();
    }
    if (t == 0) partial[blockIdx.x] = sm[0];
}

// K3b: exclusive scan of partial[SCAN_BLOCKS] (single tiny block)
__global__ __launch_bounds__(256) void scan_partials_kernel(int* __restrict__ partial) {
    __shared__ int sm[256];
    int t = threadIdx.x;
    int v = (t < SCAN_BLOCKS) ? partial[t] : 0;
    sm[t] = v;
    __syncthreads();
    for (int s = 1; s < 256; s <<= 1) {
        int x = (t >= s) ? sm[t - s] : 0;
        __syncthreads();
        sm[t] += x;
        __syncthreads();
    }
    if (t < SCAN_BLOCKS) partial[t] = sm[t] - v;   // exclusive
}

// K3c: downsweep — block-local exclusive scan + partial prefix -> off, cursor
__global__ __launch_bounds__(256) void scan_down_kernel(const int* __restrict__ deg,
                                                        const int* __restrict__ partial,
                                                        int* __restrict__ off,
                                                        int* __restrict__ cursor) {
    __shared__ int sm[256];
    int t = threadIdx.x;
    int i = blockIdx.x * 256 + t;
    int v = deg[i];
    sm[t] = v;
    __syncthreads();
    for (int s = 1; s < 256; s <<= 1) {
        int x = (t >= s) ? sm[t - s] : 0;
        __syncthreads();
        sm[t] += x;
        __syncthreads();
    }
    if (i < N_NODES) {
        int o = partial[blockIdx.x] + sm[t] - v;   // global exclusive prefix
        off[i] = o;
        cursor[i] = o;
    }
    if (i == 0) off[N_NODES] = N_EDGES;            // total is compile-time constant
}

// K4: fill CSR edge list (src ids grouped by dst)
__global__ __launch_bounds__(256) void fill_kernel(const int* __restrict__ src,
                                                   const int* __restrict__ dst,
                                                   int* __restrict__ cursor,
                                                   int* __restrict__ esrc) {
    int e = blockIdx.x * 256 + threadIdx.x;
    if (e < N_EDGES) {
        int p = atomicAdd(&cursor[dst[e]], 1);
        esrc[p] = src[e];
    }
}

// K6: Y = feat @ W  (f32 FMA, bf16 output).  Col-split: each block does a
// 64-col half of W -> 32 KB LDS -> 5 blocks/CU (vs 2 at 64 KB in R3).
// 8 rows/thread halves W-LDS bytes per FLOP (0.5 B/FLOP < 85 B/cyc ceiling),
// fixing R3's LDS-BW co-limit (VALUBusy was 26%).
__global__ __launch_bounds__(256) void gemm_feat_kernel(
        const float4* __restrict__ feat4,    // [N][32]
        const float4* __restrict__ W4,       // [128][32]
        unsigned short* __restrict__ Y) {    // [N][128] bf16
    __shared__ float4 Wl[128 * 16];          // 32 KB: Wl[k*16 + c4l] = W[k][cols]
    const int ch = blockIdx.x & 1;           // which 64-col half
    const int rb = blockIdx.x >> 1;
    for (int i = threadIdx.x; i < 128 * 16; i += 256)
        Wl[i] = W4[(i >> 4) * 32 + ch * 16 + (i & 15)];
    __syncthreads();

    const int c4l  = threadIdx.x & 15;       // col-quad within half
    const int col4 = ch * 16 + c4l;          // global col-quad 0..31
    const int rs   = threadIdx.x >> 4;       // 0..15 row slot
    const int row0 = rb * ROWS_PB + rs * 8;
    if (row0 >= N_NODES) return;             // N_NODES % 8 == 0 -> all-or-none

    float4 acc[8];
    #pragma unroll
    for (int i = 0; i < 8; ++i) acc[i] = make_float4(0.f, 0.f, 0.f, 0.f);
    const float4* ab = feat4 + (size_t)row0 * 32;

    for (int k4 = 0; k4 < 32; ++k4) {
        float4 w0 = Wl[(k4 * 4 + 0) * 16 + c4l];
        float4 w1 = Wl[(k4 * 4 + 1) * 16 + c4l];
        float4 w2 = Wl[(k4 * 4 + 2) * 16 + c4l];
        float4 w3 = Wl[(k4 * 4 + 3) * 16 + c4l];
        #pragma unroll
        for (int i = 0; i < 8; ++i) {
            float4 A = ab[i * 32 + k4];
            acc[i].x += A.x*w0.x + A.y*w1.x + A.z*w2.x + A.w*w3.x;
            acc[i].y += A.x*w0.y + A.y*w1.y + A.z*w2.y + A.w*w3.y;
            acc[i].z += A.x*w0.z + A.y*w1.z + A.z*w2.z + A.w*w3.z;
            acc[i].w += A.x*w0.w + A.y*w1.w + A.z*w2.w + A.w*w3.w;
        }
    }
    #pragma unroll
    for (int i = 0; i < 8; ++i) {
        ushort4 o;
        o.x = f2bf(acc[i].x); o.y = f2bf(acc[i].y);
        o.z = f2bf(acc[i].z); o.w = f2bf(acc[i].w);
        ((ushort4*)(Y + (size_t)(row0 + i) * D))[col4] = o;
    }
}

// K5: per-node gather-sum over bf16 Y (f32 accumulate) + b, write f32 out.
// One wave per node; lane owns 2 cols (one packed uint = 2 bf16 per row).
// 256 B/row coalesced; Y (12.8 MB) is L2/L3-hot. No atomics.
__global__ __launch_bounds__(256) void gather_kernel(
        const unsigned* __restrict__ Y32,    // [N][64] packed bf16x2
        const int* __restrict__ off,
        const int* __restrict__ esrc,
        const float2* __restrict__ b2,
        float2* __restrict__ out2) {
    int node = (blockIdx.x * 256 + threadIdx.x) >> 6;
    int lane = threadIdx.x & 63;
    if (node >= N_NODES) return;
    int beg = off[node], end = off[node + 1];
    float ax = 0.f, ay = 0.f;
    int p = beg;
    for (; p + 4 <= end; p += 4) {           // 4x unroll for load ILP
        int s0 = esrc[p], s1 = esrc[p + 1], s2 = esrc[p + 2], s3 = esrc[p + 3];
        unsigned v0 = Y32[(size_t)s0 * 64 + lane];
        unsigned v1 = Y32[(size_t)s1 * 64 + lane];
        unsigned v2 = Y32[(size_t)s2 * 64 + lane];
        unsigned v3 = Y32[(size_t)s3 * 64 + lane];
        ax += __uint_as_float(v0 << 16) + __uint_as_float(v1 << 16)
            + __uint_as_float(v2 << 16) + __uint_as_float(v3 << 16);
        ay += __uint_as_float(v0 & 0xFFFF0000u) + __uint_as_float(v1 & 0xFFFF0000u)
            + __uint_as_float(v2 & 0xFFFF0000u) + __uint_as_float(v3 & 0xFFFF0000u);
    }
    for (; p < end; ++p) {
        unsigned v = Y32[(size_t)esrc[p] * 64 + lane];
        ax += __uint_as_float(v << 16);
        ay += __uint_as_float(v & 0xFFFF0000u);
    }
    float2 bb = b2[lane];
    out2[(size_t)node * 64 + lane] = make_float2(ax + bb.x, ay + bb.y);
}

// ---------------------------------------------------------------------------
extern "C" void kernel_launch(void* const* d_in, const int* in_sizes, int n_in,
                              void* d_out, int out_size, void* d_ws, size_t ws_size,
                              hipStream_t stream) {
    const float* feat = (const float*)d_in[0];   // [50000,128] f32
    const int*   src  = (const int*)d_in[1];     // [640000] int32
    const int*   dst  = (const int*)d_in[2];     // [640000] int32
    const float* W    = (const float*)d_in[3];   // [128,128] f32
    const float* b    = (const float*)d_in[4];   // [1,128]   f32
    float* out = (float*)d_out;                  // [50000,128] f32

    unsigned short* Y = (unsigned short*)d_ws;   // 12.8 MB bf16
    int* deg     = (int*)(Y + (size_t)N_NODES * D);
    int* off     = deg + DEG_PAD;
    int* cursor  = off + OFF_PAD;
    int* partial = cursor + OFF_PAD;
    int* esrc    = partial + 256;

    zero_deg_kernel<<<(DEG_PAD / 4 + 255) / 256, 256, 0, stream>>>((int4*)deg);
    hist_kernel<<<(N_EDGES + 255) / 256, 256, 0, stream>>>(dst, deg);
    scan_reduce_kernel<<<SCAN_BLOCKS, 256, 0, stream>>>(deg, partial);
    scan_partials_kernel<<<1, 256, 0, stream>>>(partial);
    scan_down_kernel<<<SCAN_BLOCKS, 256, 0, stream>>>(deg, partial, off, cursor);
    fill_kernel<<<(N_EDGES + 255) / 256, 256, 0, stream>>>(src, dst, cursor, esrc);
    gemm_feat_kernel<<<((N_NODES + ROWS_PB - 1) / ROWS_PB) * 2, 256, 0, stream>>>(
        (const float4*)feat, (const float4*)W, Y);
    gather_kernel<<<(N_NODES * 64 + 255) / 256, 256, 0, stream>>>(
        (const unsigned*)Y, off, esrc, (const float2*)b, (float2*)out);
}

// Round 5
// 201.933 us; speedup vs baseline: 5.9798x; 1.0951x over previous
//
#include <hip/hip_runtime.h>

#define N_NODES 50000
#define N_EDGES 640000
#define D 128               // D_IN == D_OUT == 128

// ---------------------------------------------------------------------------
// Pipeline (transform-first): out = segment_sum((feat @ W)[src]) + b
//   wcvt:      W (f32) -> Wf (bf16, B-fragment order)         [32 KB]
//   gemm_mfma: Y = feat @ W   via mfma_f32_16x16x32_bf16, Y bf16 [12.8 MB]
//   CSR build: zero/hist/scan3/fill  (int atomics only)
//   gather:    out[d] = sum Y[src[e]] + b   (f32 accum, no atomics)
// Workspace: Y bf16, then deg/off/cursor/partial/esrc ints, then Wf.
// ---------------------------------------------------------------------------
#define DEG_PAD 50176       // 196 * 256
#define OFF_PAD 50048
#define SCAN_BLOCKS 196
#define N_TILES 3125        // 50000 / 16
#define TILES_PB 5          // row-tiles per block -> grid 625

typedef __attribute__((ext_vector_type(8))) short short8;   // 8 bf16 (4 VGPRs)
typedef __attribute__((ext_vector_type(4))) float f32x4;    // MFMA C/D

// pack two f32 into bf16x2 (round-half-up in magnitude: +0x8000 then trunc;
// one v_perm_b32 grabs the top16 of each)
static __device__ inline unsigned pkbf(float lo, float hi) {
    unsigned a = __float_as_uint(lo) + 0x8000u;
    unsigned b = __float_as_uint(hi) + 0x8000u;
    return __builtin_amdgcn_perm(b, a, 0x07060302);  // [b.hi16 : a.hi16]
}
static __device__ inline unsigned short f2bf(float f) {
    return (unsigned short)((__float_as_uint(f) + 0x8000u) >> 16);
}

// K0: W (f32 row-major [k][c]) -> Wf bf16 in B-fragment order.
// Entry e = ((t*8+nt)*16+n)*4+q holds B[k=t*32+q*8+j][c=nt*16+n], j=0..7.
__global__ __launch_bounds__(256) void wcvt_kernel(const float* __restrict__ W,
                                                   uint4* __restrict__ Wf) {
    int e = blockIdx.x * 256 + threadIdx.x;
    if (e >= 2048) return;
    int q  = e & 3;
    int n  = (e >> 2) & 15;
    int nt = (e >> 6) & 7;
    int t  = e >> 9;
    const float* p = W + (t * 32 + q * 8) * D + nt * 16 + n;
    unsigned u[8];
    #pragma unroll
    for (int j = 0; j < 8; ++j) u[j] = __float_as_uint(p[j * D]) + 0x8000u;
    uint4 o;
    o.x = __builtin_amdgcn_perm(u[1], u[0], 0x07060302);
    o.y = __builtin_amdgcn_perm(u[3], u[2], 0x07060302);
    o.z = __builtin_amdgcn_perm(u[5], u[4], 0x07060302);
    o.w = __builtin_amdgcn_perm(u[7], u[6], 0x07060302);
    Wf[e] = o;
}

// K1: zero the degree array (ws is poisoned 0xAA every call)
__global__ __launch_bounds__(256) void zero_deg_kernel(int4* __restrict__ p) {
    int i = blockIdx.x * 256 + threadIdx.x;
    if (i < DEG_PAD / 4) p[i] = make_int4(0, 0, 0, 0);
}

// K2: histogram of dst -> deg
__global__ __launch_bounds__(256) void hist_kernel(const int* __restrict__ dst,
                                                   int* __restrict__ deg) {
    int e = blockIdx.x * 256 + threadIdx.x;
    if (e < N_EDGES) atomicAdd(&deg[dst[e]], 1);
}

// K3a: per-block reduce of deg -> partial
__global__ __launch_bounds__(256) void scan_reduce_kernel(const int* __restrict__ deg,
                                                          int* __restrict__ partial) {
    __shared__ int sm[256];
    int t = threadIdx.x;
    sm[t] = deg[blockIdx.x * 256 + t];
    __syncthreads();
    for (int s = 128; s > 0; s >>= 1) {
        if (t < s) sm[t] += sm[t + s];
        __syncthreads();
    }
    if (t == 0) partial[blockIdx.x] = sm[0];
}

// K3b: exclusive scan of partials (single tiny block)
__global__ __launch_bounds__(256) void scan_partials_kernel(int* __restrict__ partial) {
    __shared__ int sm[256];
    int t = threadIdx.x;
    int v = (t < SCAN_BLOCKS) ? partial[t] : 0;
    sm[t] = v;
    __syncthreads();
    for (int s = 1; s < 256; s <<= 1) {
        int x = (t >= s) ? sm[t - s] : 0;
        __syncthreads();
        sm[t] += x;
        __syncthreads();
    }
    if (t < SCAN_BLOCKS) partial[t] = sm[t] - v;
}

// K3c: downsweep -> off, cursor
__global__ __launch_bounds__(256) void scan_down_kernel(const int* __restrict__ deg,
                                                        const int* __restrict__ partial,
                                                        int* __restrict__ off,
                                                        int* __restrict__ cursor) {
    __shared__ int sm[256];
    int t = threadIdx.x;
    int i = blockIdx.x * 256 + t;
    int v = deg[i];
    sm[t] = v;
    __syncthreads();
    for (int s = 1; s < 256; s <<= 1) {
        int x = (t >= s) ? sm[t - s] : 0;
        __syncthreads();
        sm[t] += x;
        __syncthreads();
    }
    if (i < N_NODES) {
        int o = partial[blockIdx.x] + sm[t] - v;
        off[i] = o;
        cursor[i] = o;
    }
    if (i == 0) off[N_NODES] = N_EDGES;
}

// K4: fill CSR edge list (src ids grouped by dst)
__global__ __launch_bounds__(256) void fill_kernel(const int* __restrict__ src,
                                                   const int* __restrict__ dst,
                                                   int* __restrict__ cursor,
                                                   int* __restrict__ esrc) {
    int e = blockIdx.x * 256 + threadIdx.x;
    if (e < N_EDGES) {
        int p = atomicAdd(&cursor[dst[e]], 1);
        esrc[p] = src[e];
    }
}

// K6: Y = feat @ W via bf16 MFMA. 4 waves/block; wave owns 2 col-tiles
// (B frags register-resident), loops 5 row-tiles. No LDS, no syncthreads.
// A-frag: lane holds A[m=lane&15][k=q*8+j] -> 8 consecutive floats of row m.
// C/D:    col=lane&15, row=q*4+reg.
__global__ __launch_bounds__(256) void gemm_mfma_kernel(
        const float* __restrict__ feat,
        const uint4* __restrict__ Wf,
        unsigned short* __restrict__ Y) {
    const int wave = threadIdx.x >> 6;
    const int lane = threadIdx.x & 63;
    const int n = lane & 15;
    const int q = lane >> 4;

    short8 bfrag[4][2];                      // [ktile][which ntile of pair]
    #pragma unroll
    for (int t = 0; t < 4; ++t) {
        #pragma unroll
        for (int p = 0; p < 2; ++p) {
            int nt = wave * 2 + p;
            uint4 raw = Wf[(((t * 8 + nt) * 16 + n) << 2) + q];
            bfrag[t][p] = *(const short8*)&raw;
        }
    }

    #pragma unroll
    for (int r = 0; r < TILES_PB; ++r) {
        int tile = blockIdx.x * TILES_PB + r;       // grid 625 -> exactly 3125
        const float* ap = feat + (size_t)(tile * 16 + n) * D + q * 8;
        f32x4 acc0 = {0.f, 0.f, 0.f, 0.f};
        f32x4 acc1 = {0.f, 0.f, 0.f, 0.f};
        #pragma unroll
        for (int t = 0; t < 4; ++t) {
            float4 f0 = *(const float4*)(ap + t * 32);
            float4 f1 = *(const float4*)(ap + t * 32 + 4);
            int4 pa;
            pa.x = (int)pkbf(f0.x, f0.y);
            pa.y = (int)pkbf(f0.z, f0.w);
            pa.z = (int)pkbf(f1.x, f1.y);
            pa.w = (int)pkbf(f1.z, f1.w);
            short8 afrag = *(const short8*)&pa;
            acc0 = __builtin_amdgcn_mfma_f32_16x16x32_bf16(afrag, bfrag[t][0], acc0, 0, 0, 0);
            acc1 = __builtin_amdgcn_mfma_f32_16x16x32_bf16(afrag, bfrag[t][1], acc1, 0, 0, 0);
        }
        unsigned short* yp = Y + (size_t)(tile * 16 + q * 4) * D + n;
        #pragma unroll
        for (int i = 0; i < 4; ++i) {
            yp[(size_t)i * D + wave * 32]      = f2bf(acc0[i]);
            yp[(size_t)i * D + wave * 32 + 16] = f2bf(acc1[i]);
        }
    }
}

// K5: per-node gather-sum over bf16 Y (f32 accumulate) + b, write f32 out.
__global__ __launch_bounds__(256) void gather_kernel(
        const unsigned* __restrict__ Y32,    // [N][64] packed bf16x2
        const int* __restrict__ off,
        const int* __restrict__ esrc,
        const float2* __restrict__ b2,
        float2* __restrict__ out2) {
    int node = (blockIdx.x * 256 + threadIdx.x) >> 6;
    int lane = threadIdx.x & 63;
    if (node >= N_NODES) return;
    int beg = off[node], end = off[node + 1];
    float ax = 0.f, ay = 0.f;
    int p = beg;
    for (; p + 4 <= end; p += 4) {
        int s0 = esrc[p], s1 = esrc[p + 1], s2 = esrc[p + 2], s3 = esrc[p + 3];
        unsigned v0 = Y32[(size_t)s0 * 64 + lane];
        unsigned v1 = Y32[(size_t)s1 * 64 + lane];
        unsigned v2 = Y32[(size_t)s2 * 64 + lane];
        unsigned v3 = Y32[(size_t)s3 * 64 + lane];
        ax += __uint_as_float(v0 << 16) + __uint_as_float(v1 << 16)
            + __uint_as_float(v2 << 16) + __uint_as_float(v3 << 16);
        ay += __uint_as_float(v0 & 0xFFFF0000u) + __uint_as_float(v1 & 0xFFFF0000u)
            + __uint_as_float(v2 & 0xFFFF0000u) + __uint_as_float(v3 & 0xFFFF0000u);
    }
    for (; p < end; ++p) {
        unsigned v = Y32[(size_t)esrc[p] * 64 + lane];
        ax += __uint_as_float(v << 16);
        ay += __uint_as_float(v & 0xFFFF0000u);
    }
    float2 bb = b2[lane];
    out2[(size_t)node * 64 + lane] = make_float2(ax + bb.x, ay + bb.y);
}

// ---------------------------------------------------------------------------
extern "C" void kernel_launch(void* const* d_in, const int* in_sizes, int n_in,
                              void* d_out, int out_size, void* d_ws, size_t ws_size,
                              hipStream_t stream) {
    const float* feat = (const float*)d_in[0];   // [50000,128] f32
    const int*   src  = (const int*)d_in[1];     // [640000] int32
    const int*   dst  = (const int*)d_in[2];     // [640000] int32
    const float* W    = (const float*)d_in[3];   // [128,128] f32
    const float* b    = (const float*)d_in[4];   // [1,128]   f32
    float* out = (float*)d_out;                  // [50000,128] f32

    unsigned short* Y = (unsigned short*)d_ws;   // 12.8 MB bf16
    int* deg     = (int*)(Y + (size_t)N_NODES * D);
    int* off     = deg + DEG_PAD;
    int* cursor  = off + OFF_PAD;
    int* partial = cursor + OFF_PAD;
    int* esrc    = partial + 256;
    uint4* Wf    = (uint4*)(esrc + N_EDGES);     // 32 KB bf16 fragments

    wcvt_kernel<<<8, 256, 0, stream>>>(W, Wf);
    zero_deg_kernel<<<(DEG_PAD / 4 + 255) / 256, 256, 0, stream>>>((int4*)deg);
    hist_kernel<<<(N_EDGES + 255) / 256, 256, 0, stream>>>(dst, deg);
    scan_reduce_kernel<<<SCAN_BLOCKS, 256, 0, stream>>>(deg, partial);
    scan_partials_kernel<<<1, 256, 0, stream>>>(partial);
    scan_down_kernel<<<SCAN_BLOCKS, 256, 0, stream>>>(deg, partial, off, cursor);
    fill_kernel<<<(N_EDGES + 255) / 256, 256, 0, stream>>>(src, dst, cursor, esrc);
    gemm_mfma_kernel<<<N_TILES / TILES_PB, 256, 0, stream>>>(
        feat, Wf, Y);
    gather_kernel<<<(N_NODES * 64 + 255) / 256, 256, 0, stream>>>(
        (const unsigned*)Y, off, esrc, (const float2*)b, (float2*)out);
}

// Round 6
// 189.012 us; speedup vs baseline: 6.3886x; 1.0684x over previous
//
#include <hip/hip_runtime.h>

#define N_NODES 50000
#define N_EDGES 640000
#define D 128               // D_IN == D_OUT == 128

// ---------------------------------------------------------------------------
// Pipeline (transform-first): out = segment_sum((feat @ W)[src]) + b
//   D1 zero_wcvt:  zero deg  ||  W (f32) -> Wf (bf16 B-fragments)
//   D2 hist:       deg histogram of dst (int atomics)
//   D3-5 scan:     reduce / scan partials / downsweep  -> off, cursor
//   D6 fill_gemm:  CSR fill (atomics)  ||  Y = feat @ W via bf16 MFMA
//   D7 gather:     out[d] = sum Y[src[e]] + b  (f32 accum, no atomics)
// Workspace: Y bf16 [12.8MB], deg/off/cursor/partial/esrc ints, Wf frags.
// ---------------------------------------------------------------------------
#define DEG_PAD 50176       // 196 * 256
#define OFF_PAD 50048
#define SCAN_BLOCKS 196
#define N_TILES 3125        // 50000 / 16
#define TILES_PB 5          // row-tiles per gemm block -> 625 gemm blocks
#define GEMM_BLOCKS (N_TILES / TILES_PB)
#define FILL_BLOCKS ((N_EDGES + 255) / 256)

typedef __attribute__((ext_vector_type(8))) short short8;   // 8 bf16 (4 VGPRs)
typedef __attribute__((ext_vector_type(4))) float f32x4;    // MFMA C/D

// pack two f32 into bf16x2 (+0x8000 round-half-up, v_perm grabs top16s)
static __device__ inline unsigned pkbf(float lo, float hi) {
    unsigned a = __float_as_uint(lo) + 0x8000u;
    unsigned b = __float_as_uint(hi) + 0x8000u;
    return __builtin_amdgcn_perm(b, a, 0x07060302);
}
static __device__ inline unsigned short f2bf(float f) {
    return (unsigned short)((__float_as_uint(f) + 0x8000u) >> 16);
}

// D1: zero deg (49 blocks)  ||  wcvt (8 blocks).
// Wf entry e = ((t*8+nt)*16+n)*4+q holds B[k=t*32+q*8+j][c=nt*16+n], j=0..7.
__global__ __launch_bounds__(256) void zero_wcvt_kernel(int4* __restrict__ deg4,
                                                        const float* __restrict__ W,
                                                        uint4* __restrict__ Wf) {
    if (blockIdx.x < 8) {
        int e = blockIdx.x * 256 + threadIdx.x;
        int q  = e & 3;
        int n  = (e >> 2) & 15;
        int nt = (e >> 6) & 7;
        int t  = e >> 9;
        const float* p = W + (t * 32 + q * 8) * D + nt * 16 + n;
        unsigned u[8];
        #pragma unroll
        for (int j = 0; j < 8; ++j) u[j] = __float_as_uint(p[j * D]) + 0x8000u;
        uint4 o;
        o.x = __builtin_amdgcn_perm(u[1], u[0], 0x07060302);
        o.y = __builtin_amdgcn_perm(u[3], u[2], 0x07060302);
        o.z = __builtin_amdgcn_perm(u[5], u[4], 0x07060302);
        o.w = __builtin_amdgcn_perm(u[7], u[6], 0x07060302);
        Wf[e] = o;
    } else {
        int i = (blockIdx.x - 8) * 256 + threadIdx.x;
        if (i < DEG_PAD / 4) deg4[i] = make_int4(0, 0, 0, 0);
    }
}

// D2: histogram of dst -> deg
__global__ __launch_bounds__(256) void hist_kernel(const int* __restrict__ dst,
                                                   int* __restrict__ deg) {
    int e = blockIdx.x * 256 + threadIdx.x;
    if (e < N_EDGES) atomicAdd(&deg[dst[e]], 1);
}

// D3: per-block reduce of deg -> partial
__global__ __launch_bounds__(256) void scan_reduce_kernel(const int* __restrict__ deg,
                                                          int* __restrict__ partial) {
    __shared__ int sm[256];
    int t = threadIdx.x;
    sm[t] = deg[blockIdx.x * 256 + t];
    __syncthreads();
    for (int s = 128; s > 0; s >>= 1) {
        if (t < s) sm[t] += sm[t + s];
        __syncthreads();
    }
    if (t == 0) partial[blockIdx.x] = sm[0];
}

// D4: exclusive scan of partials (single tiny block)
__global__ __launch_bounds__(256) void scan_partials_kernel(int* __restrict__ partial) {
    __shared__ int sm[256];
    int t = threadIdx.x;
    int v = (t < SCAN_BLOCKS) ? partial[t] : 0;
    sm[t] = v;
    __syncthreads();
    for (int s = 1; s < 256; s <<= 1) {
        int x = (t >= s) ? sm[t - s] : 0;
        __syncthreads();
        sm[t] += x;
        __syncthreads();
    }
    if (t < SCAN_BLOCKS) partial[t] = sm[t] - v;
}

// D5: downsweep -> off, cursor
__global__ __launch_bounds__(256) void scan_down_kernel(const int* __restrict__ deg,
                                                        const int* __restrict__ partial,
                                                        int* __restrict__ off,
                                                        int* __restrict__ cursor) {
    __shared__ int sm[256];
    int t = threadIdx.x;
    int i = blockIdx.x * 256 + t;
    int v = deg[i];
    sm[t] = v;
    __syncthreads();
    for (int s = 1; s < 256; s <<= 1) {
        int x = (t >= s) ? sm[t - s] : 0;
        __syncthreads();
        sm[t] += x;
        __syncthreads();
    }
    if (i < N_NODES) {
        int o = partial[blockIdx.x] + sm[t] - v;
        off[i] = o;
        cursor[i] = o;
    }
    if (i == 0) off[N_NODES] = N_EDGES;
}

// D6: gemm (625 blocks)  ||  CSR fill (2500 blocks). Independent work fused
// into one dispatch: gemm is MFMA/latency-bound, fill is atomic-return-bound
// -> overlap. gemm: 4 waves/block, wave owns 2 col-tiles (B frags in regs),
// loops 5 row-tiles; no LDS. A-frag: lane(n,q) holds A[m=n][k=q*8+j].
// C/D: col=lane&15, row=q*4+reg.
__global__ __launch_bounds__(256) void fill_gemm_kernel(
        const int* __restrict__ src,
        const int* __restrict__ dst,
        int* __restrict__ cursor,
        int* __restrict__ esrc,
        const float* __restrict__ feat,
        const uint4* __restrict__ Wf,
        unsigned short* __restrict__ Y) {
    if (blockIdx.x < GEMM_BLOCKS) {
        const int wave = threadIdx.x >> 6;
        const int lane = threadIdx.x & 63;
        const int n = lane & 15;
        const int q = lane >> 4;

        short8 bfrag[4][2];
        #pragma unroll
        for (int t = 0; t < 4; ++t) {
            #pragma unroll
            for (int p = 0; p < 2; ++p) {
                int nt = wave * 2 + p;
                uint4 raw = Wf[(((t * 8 + nt) * 16 + n) << 2) + q];
                bfrag[t][p] = *(const short8*)&raw;
            }
        }

        #pragma unroll
        for (int r = 0; r < TILES_PB; ++r) {
            int tile = blockIdx.x * TILES_PB + r;
            const float* ap = feat + (size_t)(tile * 16 + n) * D + q * 8;
            f32x4 acc0 = {0.f, 0.f, 0.f, 0.f};
            f32x4 acc1 = {0.f, 0.f, 0.f, 0.f};
            #pragma unroll
            for (int t = 0; t < 4; ++t) {
                float4 f0 = *(const float4*)(ap + t * 32);
                float4 f1 = *(const float4*)(ap + t * 32 + 4);
                int4 pa;
                pa.x = (int)pkbf(f0.x, f0.y);
                pa.y = (int)pkbf(f0.z, f0.w);
                pa.z = (int)pkbf(f1.x, f1.y);
                pa.w = (int)pkbf(f1.z, f1.w);
                short8 afrag = *(const short8*)&pa;
                acc0 = __builtin_amdgcn_mfma_f32_16x16x32_bf16(afrag, bfrag[t][0], acc0, 0, 0, 0);
                acc1 = __builtin_amdgcn_mfma_f32_16x16x32_bf16(afrag, bfrag[t][1], acc1, 0, 0, 0);
            }
            unsigned short* yp = Y + (size_t)(tile * 16 + q * 4) * D + n;
            #pragma unroll
            for (int i = 0; i < 4; ++i) {
                yp[(size_t)i * D + wave * 32]      = f2bf(acc0[i]);
                yp[(size_t)i * D + wave * 32 + 16] = f2bf(acc1[i]);
            }
        }
    } else {
        int e = (blockIdx.x - GEMM_BLOCKS) * 256 + threadIdx.x;
        if (e < N_EDGES) {
            int p = atomicAdd(&cursor[dst[e]], 1);
            esrc[p] = src[e];
        }
    }
}

// D7: per-node gather-sum over bf16 Y (f32 accum) + b -> f32 out.
// One wave per node; lane owns 2 packed cols (wave = full 256B row).
// Edge ids staged cooperatively (coalesced esrc load, shfl broadcast) so
// the row-gather loads have no load->load dependence -> deep MLP.
__global__ __launch_bounds__(256) void gather_kernel(
        const unsigned* __restrict__ Y32,    // [N][64] packed bf16x2
        const int* __restrict__ off,
        const int* __restrict__ esrc,
        const float2* __restrict__ b2,
        float2* __restrict__ out2) {
    int node = (blockIdx.x * 256 + threadIdx.x) >> 6;
    int lane = threadIdx.x & 63;
    if (node >= N_NODES) return;
    int beg = off[node], end = off[node + 1];
    float ax = 0.f, ay = 0.f;
    for (int base = beg; base < end; base += 64) {
        int cnt = end - base;
        if (cnt > 64) cnt = 64;
        int eid = (base + lane < end) ? esrc[base + lane] : 0;
        int j = 0;
        for (; j + 4 <= cnt; j += 4) {
            int s0 = __shfl(eid, j);
            int s1 = __shfl(eid, j + 1);
            int s2 = __shfl(eid, j + 2);
            int s3 = __shfl(eid, j + 3);
            unsigned v0 = Y32[(size_t)s0 * 64 + lane];
            unsigned v1 = Y32[(size_t)s1 * 64 + lane];
            unsigned v2 = Y32[(size_t)s2 * 64 + lane];
            unsigned v3 = Y32[(size_t)s3 * 64 + lane];
            ax += __uint_as_float(v0 << 16) + __uint_as_float(v1 << 16)
                + __uint_as_float(v2 << 16) + __uint_as_float(v3 << 16);
            ay += __uint_as_float(v0 & 0xFFFF0000u) + __uint_as_float(v1 & 0xFFFF0000u)
                + __uint_as_float(v2 & 0xFFFF0000u) + __uint_as_float(v3 & 0xFFFF0000u);
        }
        for (; j < cnt; ++j) {
            int s = __shfl(eid, j);
            unsigned v = Y32[(size_t)s * 64 + lane];
            ax += __uint_as_float(v << 16);
            ay += __uint_as_float(v & 0xFFFF0000u);
        }
    }
    float2 bb = b2[lane];
    out2[(size_t)node * 64 + lane] = make_float2(ax + bb.x, ay + bb.y);
}

// ---------------------------------------------------------------------------
extern "C" void kernel_launch(void* const* d_in, const int* in_sizes, int n_in,
                              void* d_out, int out_size, void* d_ws, size_t ws_size,
                              hipStream_t stream) {
    const float* feat = (const float*)d_in[0];   // [50000,128] f32
    const int*   src  = (const int*)d_in[1];     // [640000] int32
    const int*   dst  = (const int*)d_in[2];     // [640000] int32
    const float* W    = (const float*)d_in[3];   // [128,128] f32
    const float* b    = (const float*)d_in[4];   // [1,128]   f32
    float* out = (float*)d_out;                  // [50000,128] f32

    unsigned short* Y = (unsigned short*)d_ws;   // 12.8 MB bf16
    int* deg     = (int*)(Y + (size_t)N_NODES * D);
    int* off     = deg + DEG_PAD;
    int* cursor  = off + OFF_PAD;
    int* partial = cursor + OFF_PAD;
    int* esrc    = partial + 256;
    uint4* Wf    = (uint4*)(esrc + N_EDGES);     // 32 KB bf16 fragments

    zero_wcvt_kernel<<<8 + DEG_PAD / 4 / 256, 256, 0, stream>>>((int4*)deg, W, Wf);
    hist_kernel<<<(N_EDGES + 255) / 256, 256, 0, stream>>>(dst, deg);
    scan_reduce_kernel<<<SCAN_BLOCKS, 256, 0, stream>>>(deg, partial);
    scan_partials_kernel<<<1, 256, 0, stream>>>(partial);
    scan_down_kernel<<<SCAN_BLOCKS, 256, 0, stream>>>(deg, partial, off, cursor);
    fill_gemm_kernel<<<GEMM_BLOCKS + FILL_BLOCKS, 256, 0, stream>>>(
        src, dst, cursor, esrc, feat, Wf, Y);
    gather_kernel<<<(N_NODES * 64 + 255) / 256, 256, 0, stream>>>(
        (const unsigned*)Y, off, esrc, (const float2*)b, (float2*)out);
}

// Round 7
// 175.662 us; speedup vs baseline: 6.8741x; 1.0760x over previous
//
#include <hip/hip_runtime.h>

#define N_NODES 50000
#define N_EDGES 640000
#define D 128               // D_IN == D_OUT == 128

// ---------------------------------------------------------------------------
// Pipeline (transform-first): out = segment_sum((feat @ W)[src]) + b
//   D1 zero_wcvt:  zero deg  ||  W (f32) -> Wf (bf16 B-fragments)
//   D2 hist_rank:  rank[e] = atomicAdd(&deg[dst[e]],1)   (rank stored!)
//   D3-5 scan:     reduce / scan partials / downsweep -> off
//   D6 fill_gemm:  atomic-FREE CSR fill (esrc u16)  ||  Y = feat@W (MFMA)
//   D7 gather:     out[d] = sum Y[src[e]] + b  (f32 accum, no atomics)
// Workspace: Y bf16 [12.8MB], deg/off/partial/rank ints, esrc u16, Wf frags.
// ---------------------------------------------------------------------------
#define DEG_PAD 50176       // 196 * 256
#define OFF_PAD 50048
#define SCAN_BLOCKS 196
#define N_TILES 3125        // 50000 / 16
#define TILES_PB 5          // row-tiles per gemm block -> 625 gemm blocks

typedef __attribute__((ext_vector_type(8))) short short8;   // 8 bf16 (4 VGPRs)
typedef __attribute__((ext_vector_type(4))) float f32x4;    // MFMA C/D

// pack two f32 into bf16x2 (+0x8000 round-half-up, v_perm grabs top16s)
static __device__ inline unsigned pkbf(float lo, float hi) {
    unsigned a = __float_as_uint(lo) + 0x8000u;
    unsigned b = __float_as_uint(hi) + 0x8000u;
    return __builtin_amdgcn_perm(b, a, 0x07060302);
}
static __device__ inline unsigned short f2bf(float f) {
    return (unsigned short)((__float_as_uint(f) + 0x8000u) >> 16);
}

// D1: zero deg (49 blocks)  ||  wcvt (8 blocks).
// Wf entry e = ((t*8+nt)*16+n)*4+q holds B[k=t*32+q*8+j][c=nt*16+n], j=0..7.
__global__ __launch_bounds__(256) void zero_wcvt_kernel(int4* __restrict__ deg4,
                                                        const float* __restrict__ W,
                                                        uint4* __restrict__ Wf) {
    if (blockIdx.x < 8) {
        int e = blockIdx.x * 256 + threadIdx.x;
        int q  = e & 3;
        int n  = (e >> 2) & 15;
        int nt = (e >> 6) & 7;
        int t  = e >> 9;
        const float* p = W + (t * 32 + q * 8) * D + nt * 16 + n;
        unsigned u[8];
        #pragma unroll
        for (int j = 0; j < 8; ++j) u[j] = __float_as_uint(p[j * D]) + 0x8000u;
        uint4 o;
        o.x = __builtin_amdgcn_perm(u[1], u[0], 0x07060302);
        o.y = __builtin_amdgcn_perm(u[3], u[2], 0x07060302);
        o.z = __builtin_amdgcn_perm(u[5], u[4], 0x07060302);
        o.w = __builtin_amdgcn_perm(u[7], u[6], 0x07060302);
        Wf[e] = o;
    } else {
        int i = (blockIdx.x - 8) * 256 + threadIdx.x;
        if (i < DEG_PAD / 4) deg4[i] = make_int4(0, 0, 0, 0);
    }
}

// D2: histogram of dst -> deg, KEEPING the atomic's return as the edge's
// rank within its destination bucket (coalesced 4B store).
__global__ __launch_bounds__(256) void hist_rank_kernel(const int* __restrict__ dst,
                                                        int* __restrict__ deg,
                                                        int* __restrict__ rank) {
    int e = blockIdx.x * 256 + threadIdx.x;
    if (e < N_EDGES) rank[e] = atomicAdd(&deg[dst[e]], 1);
}

// D3: per-block reduce of deg -> partial
__global__ __launch_bounds__(256) void scan_reduce_kernel(const int* __restrict__ deg,
                                                          int* __restrict__ partial) {
    __shared__ int sm[256];
    int t = threadIdx.x;
    sm[t] = deg[blockIdx.x * 256 + t];
    __syncthreads();
    for (int s = 128; s > 0; s >>= 1) {
        if (t < s) sm[t] += sm[t + s];
        __syncthreads();
    }
    if (t == 0) partial[blockIdx.x] = sm[0];
}

// D4: exclusive scan of partials (single tiny block)
__global__ __launch_bounds__(256) void scan_partials_kernel(int* __restrict__ partial) {
    __shared__ int sm[256];
    int t = threadIdx.x;
    int v = (t < SCAN_BLOCKS) ? partial[t] : 0;
    sm[t] = v;
    __syncthreads();
    for (int s = 1; s < 256; s <<= 1) {
        int x = (t >= s) ? sm[t - s] : 0;
        __syncthreads();
        sm[t] += x;
        __syncthreads();
    }
    if (t < SCAN_BLOCKS) partial[t] = sm[t] - v;
}

// D5: downsweep -> off
__global__ __launch_bounds__(256) void scan_down_kernel(const int* __restrict__ deg,
                                                        const int* __restrict__ partial,
                                                        int* __restrict__ off) {
    __shared__ int sm[256];
    int t = threadIdx.x;
    int i = blockIdx.x * 256 + t;
    int v = deg[i];
    sm[t] = v;
    __syncthreads();
    for (int s = 1; s < 256; s <<= 1) {
        int x = (t >= s) ? sm[t - s] : 0;
        __syncthreads();
        sm[t] += x;
        __syncthreads();
    }
    if (i < N_NODES) off[i] = partial[blockIdx.x] + sm[t] - v;
    if (i == 0) off[N_NODES] = N_EDGES;
}

// D6: gemm (625 blocks) || atomic-free CSR fill (2500 blocks), interleaved
// (blockIdx%5==0 -> gemm) so both spread across CUs. Fill: two coalesced
// loads + L2-hot off[] read + one scattered 2B store (u16 node ids halve
// the scatter's write amplification vs 4B).
// gemm: 4 waves/block, wave owns 2 col-tiles (B frags in regs), 5 row-tiles,
// no LDS. A-frag: lane(n,q) holds A[m=n][k=q*8+j]. C/D: col=n, row=q*4+reg.
__global__ __launch_bounds__(256) void fill_gemm_kernel(
        const int* __restrict__ src,
        const int* __restrict__ dst,
        const int* __restrict__ rank,
        const int* __restrict__ off,
        unsigned short* __restrict__ esrc,
        const float* __restrict__ feat,
        const uint4* __restrict__ Wf,
        unsigned short* __restrict__ Y) {
    const int g = blockIdx.x / 5;
    const int r5 = blockIdx.x % 5;
    if (r5 == 0) {
        const int wave = threadIdx.x >> 6;
        const int lane = threadIdx.x & 63;
        const int n = lane & 15;
        const int q = lane >> 4;

        short8 bfrag[4][2];
        #pragma unroll
        for (int t = 0; t < 4; ++t) {
            #pragma unroll
            for (int p = 0; p < 2; ++p) {
                int nt = wave * 2 + p;
                uint4 raw = Wf[(((t * 8 + nt) * 16 + n) << 2) + q];
                bfrag[t][p] = *(const short8*)&raw;
            }
        }

        #pragma unroll
        for (int r = 0; r < TILES_PB; ++r) {
            int tile = g * TILES_PB + r;
            const float* ap = feat + (size_t)(tile * 16 + n) * D + q * 8;
            f32x4 acc0 = {0.f, 0.f, 0.f, 0.f};
            f32x4 acc1 = {0.f, 0.f, 0.f, 0.f};
            #pragma unroll
            for (int t = 0; t < 4; ++t) {
                float4 f0 = *(const float4*)(ap + t * 32);
                float4 f1 = *(const float4*)(ap + t * 32 + 4);
                int4 pa;
                pa.x = (int)pkbf(f0.x, f0.y);
                pa.y = (int)pkbf(f0.z, f0.w);
                pa.z = (int)pkbf(f1.x, f1.y);
                pa.w = (int)pkbf(f1.z, f1.w);
                short8 afrag = *(const short8*)&pa;
                acc0 = __builtin_amdgcn_mfma_f32_16x16x32_bf16(afrag, bfrag[t][0], acc0, 0, 0, 0);
                acc1 = __builtin_amdgcn_mfma_f32_16x16x32_bf16(afrag, bfrag[t][1], acc1, 0, 0, 0);
            }
            unsigned short* yp = Y + (size_t)(tile * 16 + q * 4) * D + n;
            #pragma unroll
            for (int i = 0; i < 4; ++i) {
                yp[(size_t)i * D + wave * 32]      = f2bf(acc0[i]);
                yp[(size_t)i * D + wave * 32 + 16] = f2bf(acc1[i]);
            }
        }
    } else {
        int e = (g * 4 + (r5 - 1)) * 256 + threadIdx.x;
        if (e < N_EDGES) {
            int d = dst[e];
            int p = off[d] + rank[e];          // no atomic: rank captured in hist
            esrc[p] = (unsigned short)src[e];
        }
    }
}

// D7: per-node gather-sum over bf16 Y (f32 accum) + b -> f32 out.
// One wave per node; lane owns 2 packed cols (wave = full 256B row).
// Edge ids staged cooperatively (coalesced u16 esrc load, shfl broadcast)
// so row-gather loads have no load->load dependence -> deep MLP.
__global__ __launch_bounds__(256) void gather_kernel(
        const unsigned* __restrict__ Y32,    // [N][64] packed bf16x2
        const int* __restrict__ off,
        const unsigned short* __restrict__ esrc,
        const float2* __restrict__ b2,
        float2* __restrict__ out2) {
    int node = (blockIdx.x * 256 + threadIdx.x) >> 6;
    int lane = threadIdx.x & 63;
    if (node >= N_NODES) return;
    int beg = off[node], end = off[node + 1];
    float ax = 0.f, ay = 0.f;
    for (int base = beg; base < end; base += 64) {
        int cnt = end - base;
        if (cnt > 64) cnt = 64;
        int eid = (base + lane < end) ? (int)esrc[base + lane] : 0;
        int j = 0;
        for (; j + 4 <= cnt; j += 4) {
            int s0 = __shfl(eid, j);
            int s1 = __shfl(eid, j + 1);
            int s2 = __shfl(eid, j + 2);
            int s3 = __shfl(eid, j + 3);
            unsigned v0 = Y32[(size_t)s0 * 64 + lane];
            unsigned v1 = Y32[(size_t)s1 * 64 + lane];
            unsigned v2 = Y32[(size_t)s2 * 64 + lane];
            unsigned v3 = Y32[(size_t)s3 * 64 + lane];
            ax += __uint_as_float(v0 << 16) + __uint_as_float(v1 << 16)
                + __uint_as_float(v2 << 16) + __uint_as_float(v3 << 16);
            ay += __uint_as_float(v0 & 0xFFFF0000u) + __uint_as_float(v1 & 0xFFFF0000u)
                + __uint_as_float(v2 & 0xFFFF0000u) + __uint_as_float(v3 & 0xFFFF0000u);
        }
        for (; j < cnt; ++j) {
            int s = __shfl(eid, j);
            unsigned v = Y32[(size_t)s * 64 + lane];
            ax += __uint_as_float(v << 16);
            ay += __uint_as_float(v & 0xFFFF0000u);
        }
    }
    float2 bb = b2[lane];
    out2[(size_t)node * 64 + lane] = make_float2(ax + bb.x, ay + bb.y);
}

// ---------------------------------------------------------------------------
extern "C" void kernel_launch(void* const* d_in, const int* in_sizes, int n_in,
                              void* d_out, int out_size, void* d_ws, size_t ws_size,
                              hipStream_t stream) {
    const float* feat = (const float*)d_in[0];   // [50000,128] f32
    const int*   src  = (const int*)d_in[1];     // [640000] int32
    const int*   dst  = (const int*)d_in[2];     // [640000] int32
    const float* W    = (const float*)d_in[3];   // [128,128] f32
    const float* b    = (const float*)d_in[4];   // [1,128]   f32
    float* out = (float*)d_out;                  // [50000,128] f32

    unsigned short* Y = (unsigned short*)d_ws;   // 12.8 MB bf16
    int* deg     = (int*)(Y + (size_t)N_NODES * D);
    int* off     = deg + DEG_PAD;
    int* partial = off + OFF_PAD;
    int* rank    = partial + 256;
    unsigned short* esrc = (unsigned short*)(rank + N_EDGES);
    uint4* Wf    = (uint4*)(esrc + N_EDGES);     // 32 KB bf16 fragments

    zero_wcvt_kernel<<<8 + DEG_PAD / 4 / 256, 256, 0, stream>>>((int4*)deg, W, Wf);
    hist_rank_kernel<<<(N_EDGES + 255) / 256, 256, 0, stream>>>(dst, deg, rank);
    scan_reduce_kernel<<<SCAN_BLOCKS, 256, 0, stream>>>(deg, partial);
    scan_partials_kernel<<<1, 256, 0, stream>>>(partial);
    scan_down_kernel<<<SCAN_BLOCKS, 256, 0, stream>>>(deg, partial, off);
    fill_gemm_kernel<<<N_TILES, 256, 0, stream>>>(   // 3125 = 625 gemm + 2500 fill
        src, dst, rank, off, esrc, feat, Wf, Y);
    gather_kernel<<<(N_NODES * 64 + 255) / 256, 256, 0, stream>>>(
        (const unsigned*)Y, off, esrc, (const float2*)b, (float2*)out);
}